// Round 7
// baseline (2556.242 us; speedup 1.0000x reference)
//
#include <hip/hip_runtime.h>
#include <hip/hip_fp16.h>
#include <math.h>

#define N_NODES 500000
#define N_EDGES 16000000

#define NBUCKET 2048           // fine bucket = dst >> 8 (256 nodes)
#define NSB 64                 // super bucket = dst >> 13 (8192 nodes)
#define NSLICE 32              // slices per super bucket in pass B
#define NB_USED 1954           // ceil(500000/256)

#define NCH_H 500
#define CHUNK_H 32000          // 500*32000 = 16M ; /4 for uint4
#define NCH_A 1000
#define CHUNK_A 16000          // 1000*16000 = 16M ; /4 for uint4
#define T_A 4000               // multisplit tile (4 per chunk)
#define T_B 4000               // multisplit tile in pass B
#define CAPQ 2112              // per-src-quarter queue cap in k_l2 (mean 2048)

// Workspace layout (bytes):
//   tot     [0,        8,192)       2048 int (fine bucket totals)
//   base    [8,192,   16,392)       2049 int
//   fineCur [16,512,  24,704)       2048 int
//   sbCur   [24,704,  24,960)       64 int (aux-relative cursors)
//   auxBase [24,960,  25,216)       64 int (aux-relative starts)
//   xh8     [4,025,600, 8,025,600)  N*8 fp8 (4 MB)
//   pairs   [8,025,664, 72,025,664) E uint (src | (dst&8191)<<19), bucketed
//                                   by fine bucket, UNSORTED within bucket
//   aux     [72,025,664, 105,625,664) 33.6 MB half-pass staging; overlaid
//   AFTER aux is dead (post passB half1):
//     h1p8  [72,025,664, 80,025,664)  N*16 fp8 (8 MB; 2 MB per src-quarter)
//     s2    [80,025,664, 96,025,664)  N*16 fp16 (16 MB)
#define OFF_TOT     0
#define OFF_BASE    8192
#define OFF_FCUR    16512
#define OFF_SBCUR   24704
#define OFF_AUXB    24960
#define OFF_XH8     4025600
#define OFF_PAIRS   8025664
#define OFF_AUX     72025664
#define OFF_H1P8    72025664
#define OFF_S2      80025664

typedef float v2f __attribute__((ext_vector_type(2)));
typedef unsigned int v4u __attribute__((ext_vector_type(4)));

static __device__ inline float2 up2(unsigned int u) {
  __half2 h = *reinterpret_cast<__half2*>(&u);
  return __half22float2(h);
}
static __device__ inline unsigned int ph2(float a, float b) {
  __half2 h = __floats2half2_rn(a, b);
  return *reinterpret_cast<unsigned int*>(&h);
}
static __device__ inline unsigned int pk_fp8x4(float a, float b, float c, float d) {
  int u = __builtin_amdgcn_cvt_pk_fp8_f32(a, b, 0, false);
  u = __builtin_amdgcn_cvt_pk_fp8_f32(c, d, u, true);
  return (unsigned int)u;
}

// ---- 0: cast x to packed fp8 ---------------------------------------------
__global__ __launch_bounds__(256) void k_xcast(const float* __restrict__ x,
                                               uint2* __restrict__ xh8) {
  int i = blockIdx.x * 256 + threadIdx.x;
  if (i >= N_NODES) return;
  const float4* xp = (const float4*)(x + (size_t)i * 8);
  float4 a = xp[0], b = xp[1];
  uint2 v;
  v.x = pk_fp8x4(a.x, a.y, a.z, a.w);
  v.y = pk_fp8x4(b.x, b.y, b.z, b.w);
  xh8[i] = v;
}

// ---- 1: fine-bucket histogram -> tot (global atomics, 2048/block) --------
__global__ __launch_bounds__(256) void k_hist(const int* __restrict__ ei,
                                              int* __restrict__ tot) {
  __shared__ int hist[NBUCKET];
  int t = threadIdx.x;
  int c = blockIdx.x;
#pragma unroll
  for (int j = 0; j < NBUCKET / 256; j++) hist[t + j * 256] = 0;
  __syncthreads();
  int e0 = c * CHUNK_H;
  const int ng = CHUNK_H / 4;
  for (int g = t; g < ng; g += 256) {
    uint4 d4 = *(const uint4*)(ei + N_EDGES + e0 + g * 4);
    atomicAdd(&hist[d4.x >> 8], 1);
    atomicAdd(&hist[d4.y >> 8], 1);
    atomicAdd(&hist[d4.z >> 8], 1);
    atomicAdd(&hist[d4.w >> 8], 1);
  }
  __syncthreads();
#pragma unroll
  for (int j = 0; j < NBUCKET / 256; j++) {
    int b = t + j * 256;
    if (hist[b]) atomicAdd(&tot[b], hist[b]);
  }
}

// ---- 2: scan tot -> base; init fineCur, sbCur, auxBase -------------------
__global__ __launch_bounds__(256) void k_scan(const int* __restrict__ tot,
                                              int* __restrict__ base,
                                              int* __restrict__ fineCur,
                                              int* __restrict__ sbCur,
                                              int* __restrict__ auxBase) {
  __shared__ int lds[256];
  int t = threadIdx.x;
  int loc[8];
  int s = 0;
#pragma unroll
  for (int j = 0; j < 8; j++) {
    loc[j] = s;
    s += tot[t * 8 + j];
  }
  lds[t] = s;
  __syncthreads();
  for (int off = 1; off < 256; off <<= 1) {
    int v = (t >= off) ? lds[t - off] : 0;
    __syncthreads();
    lds[t] += v;
    __syncthreads();
  }
  int eb = (t > 0) ? lds[t - 1] : 0;
#pragma unroll
  for (int j = 0; j < 8; j++) {
    int idx = t * 8 + j;
    int v = eb + loc[j];
    base[idx] = v;
    fineCur[idx] = v;
  }
  if (t == 255) base[NBUCKET] = lds[255];
  if (t < NSB) {
    int v = (t > 0) ? lds[t * 4 - 1] : 0;  // base[t<<5]
    if (t >= 32) v -= lds[127];            // rebase half1 to aux offset 0
    sbCur[t] = v;
    auxBase[t] = v;
  }
}

// ---- 3: pass A — LDS multisplit scatter into 32 super-bucket streams -----
__global__ __launch_bounds__(256) void k_passA(const int* __restrict__ ei,
                                               int* __restrict__ sbCur,
                                               unsigned int* __restrict__ aux,
                                               int half) {
  __shared__ unsigned int ldsW[T_A];
  __shared__ unsigned char sid[T_A];
  __shared__ int hist[4 * 32];
  __shared__ int gbase[4 * 32];
  __shared__ int loff[32];
  __shared__ int lcur[32];
  __shared__ int tot_s;
  int t = threadIdx.x;
  int c = blockIdx.x;
  int e0 = c * CHUNK_A;
  int sb0 = half * 32;
  if (t < 128) hist[t] = 0;
  __syncthreads();
  // phase 1: per-(tile,stream) counts — single pass over dst
  {
    const int ng = CHUNK_A / 4;
    for (int g = t; g < ng; g += 256) {
      uint4 d4 = *(const uint4*)(ei + N_EDGES + e0 + g * 4);
      int tile = g / (T_A / 4);   // 4-edge group fully inside one tile
      unsigned int dd[4] = {d4.x, d4.y, d4.z, d4.w};
#pragma unroll
      for (int j = 0; j < 4; j++) {
        int sb = (int)(dd[j] >> 13);
        if ((sb >> 5) == half) atomicAdd(&hist[tile * 32 + (sb & 31)], 1);
      }
    }
  }
  __syncthreads();
  // phase 2: one global reservation per stream; per-tile bases
  if (t < 32) {
    int h0 = hist[t], h1 = hist[32 + t], h2 = hist[64 + t], h3 = hist[96 + t];
    int g = atomicAdd(&sbCur[sb0 + t], h0 + h1 + h2 + h3);
    gbase[t] = g;
    gbase[32 + t] = g + h0;
    gbase[64 + t] = g + h0 + h1;
    gbase[96 + t] = g + h0 + h1 + h2;
  }
  __syncthreads();
  for (int ti = 0; ti < 4; ti++) {
    if (t == 0) {
      int r = 0;
      for (int s = 0; s < 32; s++) {
        loff[s] = r; lcur[s] = r; r += hist[ti * 32 + s];
      }
      tot_s = r;
    }
    __syncthreads();
    int tb = e0 + ti * T_A;
    const int ng = T_A / 4;
    // phase 3: permute tile into LDS by stream
    for (int g = t; g < ng; g += 256) {
      uint4 s4 = *(const uint4*)(ei + tb + g * 4);
      uint4 d4 = *(const uint4*)(ei + N_EDGES + tb + g * 4);
      unsigned int ss[4] = {s4.x, s4.y, s4.z, s4.w};
      unsigned int dd[4] = {d4.x, d4.y, d4.z, d4.w};
#pragma unroll
      for (int j = 0; j < 4; j++) {
        int sb = (int)(dd[j] >> 13);
        if ((sb >> 5) == half) {
          int sl = sb & 31;
          int pos = atomicAdd(&lcur[sl], 1);
          ldsW[pos] = ss[j] | ((dd[j] & 8191u) << 19);
          sid[pos] = (unsigned char)sl;
        }
      }
    }
    __syncthreads();
    // phase 4: coalesced copy-out per stream segment
    int tot2 = tot_s;
    for (int k = t; k < tot2; k += 256) {
      int s = sid[k];
      __builtin_nontemporal_store(ldsW[k], &aux[gbase[ti * 32 + s] + (k - loff[s])]);
    }
    __syncthreads();
  }
}

// ---- 4: pass B — LDS multisplit re-scatter into fine buckets -------------
__global__ __launch_bounds__(256) void k_passB(const unsigned int* __restrict__ aux,
                                               const int* __restrict__ base,
                                               const int* __restrict__ auxBase,
                                               int* __restrict__ fineCur,
                                               unsigned int* __restrict__ pairs,
                                               int half) {
  __shared__ unsigned int ldsW[T_B];
  __shared__ unsigned char sid[T_B];
  __shared__ int hist[4 * 32];
  __shared__ int gbase[4 * 32];
  __shared__ int loff[32];
  __shared__ int lcur[32];
  __shared__ int tot_s;
  int t = threadIdx.x;
  int sbl = blockIdx.x / NSLICE;
  int sl = blockIdx.x % NSLICE;
  int sb = half * 32 + sbl;
  int aStart = auxBase[sb];
  int len = base[(sb + 1) << 5] - base[sb << 5];
  int per = (len + NSLICE - 1) / NSLICE;
  int lo = sl * per;
  int hi = lo + per;
  if (hi > len) hi = len;
  if (lo >= hi) return;                  // uniform across block
  int nt = (hi - lo + T_B - 1) / T_B;    // <= 4 (slice ~8200 edges)
  if (t < 128) hist[t] = 0;
  __syncthreads();
  // phase 1: per-(tile,stream) counts
  for (int k = lo + t; k < hi; k += 256) {
    unsigned int w = aux[aStart + k];
    int tile = (k - lo) / T_B;
    atomicAdd(&hist[tile * 32 + (int)(w >> 27)], 1);
  }
  __syncthreads();
  // phase 2: one global reservation per fine stream; per-tile bases
  if (t < 32) {
    int h0 = hist[t], h1 = hist[32 + t], h2 = hist[64 + t], h3 = hist[96 + t];
    int g = atomicAdd(&fineCur[(sb << 5) + t], h0 + h1 + h2 + h3);
    gbase[t] = g;
    gbase[32 + t] = g + h0;
    gbase[64 + t] = g + h0 + h1;
    gbase[96 + t] = g + h0 + h1 + h2;
  }
  __syncthreads();
  for (int ti = 0; ti < nt; ti++) {
    if (t == 0) {
      int r = 0;
      for (int s = 0; s < 32; s++) {
        loff[s] = r; lcur[s] = r; r += hist[ti * 32 + s];
      }
      tot_s = r;
    }
    __syncthreads();
    int tl = lo + ti * T_B;
    int te = tl + T_B;
    if (te > hi) te = hi;
    // phase 3: permute tile into LDS by fine stream (tile re-read is L2-hot)
    for (int k = tl + t; k < te; k += 256) {
      unsigned int w = aux[aStart + k];
      int s = (int)(w >> 27);
      int pos = atomicAdd(&lcur[s], 1);
      ldsW[pos] = w;
      sid[pos] = (unsigned char)s;
    }
    __syncthreads();
    // phase 4: coalesced copy-out per stream segment
    int tot2 = tot_s;
    for (int k = t; k < tot2; k += 256) {
      int s = sid[k];
      __builtin_nontemporal_store(ldsW[k], &pairs[gbase[ti * 32 + s] + (k - loff[s])]);
    }
    __syncthreads();
  }
}

// ---- 5: layer-1 bucket-centric aggregation (LDS atomics, no sort) --------
// Block = fine bucket (256 dst nodes). Edges streamed unsorted; fp8 feature
// gathered per edge and ds_add_f32'd into acc[f][ldst] ([f][256] layout:
// bank = ldst%32, random — avoids the 16-way conflict of row-major).
__global__ __launch_bounds__(256) void k_l1(
    const unsigned int* __restrict__ pairs, const int* __restrict__ base,
    const uint2* __restrict__ xh8, const float* __restrict__ x,
    const float* __restrict__ W1l, const float* __restrict__ W1r,
    const float* __restrict__ b1,
    const float* __restrict__ W2l, const float* __restrict__ W2r,
    v4u* __restrict__ h1p8, v4u* __restrict__ s2) {
  __shared__ float acc[8][256];
  __shared__ int deg[256];
  __shared__ float sW1l[256], sW1r[256], sb1[32], sW2l[512], sW2r[512];
  int t = threadIdx.x;
  sW1l[t] = W1l[t];
  sW1r[t] = W1r[t];
  sW2l[t] = W2l[t];  sW2l[t + 256] = W2l[t + 256];
  sW2r[t] = W2r[t];  sW2r[t + 256] = W2r[t + 256];
  if (t < 32) sb1[t] = b1[t];
#pragma unroll
  for (int f = 0; f < 8; f++) acc[f][t] = 0.0f;
  deg[t] = 0;
  __syncthreads();

  auto scat = [&](unsigned int w, uint2 g) {
    int ld = (int)((w >> 19) & 255u);
    v2f f01 = __builtin_amdgcn_cvt_pk_f32_fp8((int)g.x, false);
    v2f f23 = __builtin_amdgcn_cvt_pk_f32_fp8((int)g.x, true);
    v2f f45 = __builtin_amdgcn_cvt_pk_f32_fp8((int)g.y, false);
    v2f f67 = __builtin_amdgcn_cvt_pk_f32_fp8((int)g.y, true);
    atomicAdd(&acc[0][ld], f01.x); atomicAdd(&acc[1][ld], f01.y);
    atomicAdd(&acc[2][ld], f23.x); atomicAdd(&acc[3][ld], f23.y);
    atomicAdd(&acc[4][ld], f45.x); atomicAdd(&acc[5][ld], f45.y);
    atomicAdd(&acc[6][ld], f67.x); atomicAdd(&acc[7][ld], f67.y);
    atomicAdd(&deg[ld], 1);
  };

  int b = blockIdx.x;
  int e0 = base[b], e1 = base[b + 1];
  int kk = e0 + t;
  for (; kk + 768 < e1; kk += 1024) {
    unsigned int w0 = __builtin_nontemporal_load(&pairs[kk]);
    unsigned int w1 = __builtin_nontemporal_load(&pairs[kk + 256]);
    unsigned int w2 = __builtin_nontemporal_load(&pairs[kk + 512]);
    unsigned int w3 = __builtin_nontemporal_load(&pairs[kk + 768]);
    uint2 g0 = xh8[w0 & 0x7FFFFu], g1 = xh8[w1 & 0x7FFFFu];
    uint2 g2 = xh8[w2 & 0x7FFFFu], g3 = xh8[w3 & 0x7FFFFu];
    scat(w0, g0); scat(w1, g1); scat(w2, g2); scat(w3, g3);
  }
  for (; kk < e1; kk += 256) {
    unsigned int w = __builtin_nontemporal_load(&pairs[kk]);
    scat(w, xh8[w & 0x7FFFFu]);
  }
  __syncthreads();

  int i = b * 256 + t;
  if (i >= N_NODES) return;
  float dinv = 1.0f / fmaxf((float)deg[t], 1.0f);
  float m[8];
#pragma unroll
  for (int f = 0; f < 8; f++) m[f] = acc[f][t] * dinv;
  const float4* xp = (const float4*)(x + (size_t)i * 8);
  float4 x0 = xp[0], x1 = xp[1];
  float xv[8] = {x0.x, x0.y, x0.z, x0.w, x1.x, x1.y, x1.z, x1.w};

  float h[32];
#pragma unroll
  for (int jj = 0; jj < 32; jj++) h[jj] = sb1[jj];
#pragma unroll
  for (int k = 0; k < 8; k++) {
#pragma unroll
    for (int jj = 0; jj < 32; jj++) {
      h[jj] = fmaf(m[k], sW1l[k * 32 + jj], h[jj]);
      h[jj] = fmaf(xv[k], sW1r[k * 32 + jj], h[jj]);
    }
  }
#pragma unroll
  for (int jj = 0; jj < 32; jj++) h[jj] = fmaxf(h[jj], 0.0f);

  float p[16], s[16];
#pragma unroll
  for (int jj = 0; jj < 16; jj++) { p[jj] = 0.0f; s[jj] = 0.0f; }
#pragma unroll
  for (int k = 0; k < 32; k++) {
#pragma unroll
    for (int jj = 0; jj < 16; jj++) {
      p[jj] = fmaf(h[k], sW2l[k * 16 + jj], p[jj]);
      s[jj] = fmaf(h[k], sW2r[k * 16 + jj], s[jj]);
    }
  }
  v4u hv;
  hv.x = pk_fp8x4(p[0], p[1], p[2], p[3]);
  hv.y = pk_fp8x4(p[4], p[5], p[6], p[7]);
  hv.z = pk_fp8x4(p[8], p[9], p[10], p[11]);
  hv.w = pk_fp8x4(p[12], p[13], p[14], p[15]);
  __builtin_nontemporal_store(hv, &h1p8[i]);
  v4u slo, shi;
  slo.x = ph2(s[0], s[1]);   slo.y = ph2(s[2], s[3]);
  slo.z = ph2(s[4], s[5]);   slo.w = ph2(s[6], s[7]);
  shi.x = ph2(s[8], s[9]);   shi.y = ph2(s[10], s[11]);
  shi.z = ph2(s[12], s[13]); shi.w = ph2(s[14], s[15]);
  __builtin_nontemporal_store(slo, &s2[(size_t)i * 2]);
  __builtin_nontemporal_store(shi, &s2[(size_t)i * 2 + 1]);
}

// ---- 6: layer-2 bucket-centric aggregation, 4 src-quarter phases ---------
// Single-pass wave-aggregated multisplit (ballot + leader atomicAdd) into 4
// fixed-cap LDS queues; each phase then gathers from a 2 MB h1p8 slice.
// Queue overflow (rare, cap = mean+1.3 sigma) processes the edge
// immediately — correct, just unphased.
__global__ __launch_bounds__(256) void k_l2(
    const unsigned int* __restrict__ pairs, const int* __restrict__ base,
    const uint4* __restrict__ h1p8, const v4u* __restrict__ s2,
    const float* __restrict__ b2, const float* __restrict__ Wout,
    const float* __restrict__ bout, float* __restrict__ out) {
  __shared__ unsigned int Q[4][CAPQ];
  __shared__ float acc[16][256];
  __shared__ int deg[256];
  __shared__ int qcur[4];
  __shared__ float sb2[16], sWo[16], sbo;
  int t = threadIdx.x;
#pragma unroll
  for (int f = 0; f < 16; f++) acc[f][t] = 0.0f;
  deg[t] = 0;
  if (t < 4) qcur[t] = 0;
  if (t < 16) { sb2[t] = b2[t]; sWo[t] = Wout[t]; }
  if (t == 0) sbo = bout[0];
  __syncthreads();

  auto scat = [&](unsigned int w, uint4 g) {
    int ld = (int)((w >> 19) & 255u);
    v2f f0 = __builtin_amdgcn_cvt_pk_f32_fp8((int)g.x, false);
    v2f f1 = __builtin_amdgcn_cvt_pk_f32_fp8((int)g.x, true);
    v2f f2 = __builtin_amdgcn_cvt_pk_f32_fp8((int)g.y, false);
    v2f f3 = __builtin_amdgcn_cvt_pk_f32_fp8((int)g.y, true);
    v2f f4 = __builtin_amdgcn_cvt_pk_f32_fp8((int)g.z, false);
    v2f f5 = __builtin_amdgcn_cvt_pk_f32_fp8((int)g.z, true);
    v2f f6 = __builtin_amdgcn_cvt_pk_f32_fp8((int)g.w, false);
    v2f f7 = __builtin_amdgcn_cvt_pk_f32_fp8((int)g.w, true);
    atomicAdd(&acc[0][ld], f0.x);   atomicAdd(&acc[1][ld], f0.y);
    atomicAdd(&acc[2][ld], f1.x);   atomicAdd(&acc[3][ld], f1.y);
    atomicAdd(&acc[4][ld], f2.x);   atomicAdd(&acc[5][ld], f2.y);
    atomicAdd(&acc[6][ld], f3.x);   atomicAdd(&acc[7][ld], f3.y);
    atomicAdd(&acc[8][ld], f4.x);   atomicAdd(&acc[9][ld], f4.y);
    atomicAdd(&acc[10][ld], f5.x);  atomicAdd(&acc[11][ld], f5.y);
    atomicAdd(&acc[12][ld], f6.x);  atomicAdd(&acc[13][ld], f6.y);
    atomicAdd(&acc[14][ld], f7.x);  atomicAdd(&acc[15][ld], f7.y);
    atomicAdd(&deg[ld], 1);
  };

  int b = blockIdx.x;
  int e0 = base[b], e1 = base[b + 1];
  int lane = t & 63;
  unsigned long long ltm = (1ull << lane) - 1ull;
  int n = e1 - e0;
  int nit = (n + 255) >> 8;
  for (int it = 0; it < nit; it++) {
    int k = e0 + (it << 8) + t;
    bool v = k < e1;
    unsigned int w = v ? __builtin_nontemporal_load(&pairs[k]) : 0u;
    // quarter = src / 125000 (equal-population slices) via magic multiply
    int q = v ? (int)(((unsigned long long)(w & 0x7FFFFu) * 34360ull) >> 32) : 4;
#pragma unroll
    for (int qq = 0; qq < 4; qq++) {
      unsigned long long m = __ballot(q == qq);
      if (!m) continue;                       // ballot is wave-uniform
      int leader = __ffsll((unsigned long long)m) - 1;
      int bs = 0;
      if (lane == leader) bs = atomicAdd(&qcur[qq], (int)__popcll(m));
      bs = __shfl(bs, leader);
      if (q == qq) {
        int pos = bs + (int)__popcll(m & ltm);
        if (pos < CAPQ) Q[qq][pos] = w;
        else scat(w, h1p8[w & 0x7FFFFu]);     // overflow: process now
      }
    }
  }
  __syncthreads();
#pragma unroll
  for (int qq = 0; qq < 4; qq++) {
    int cnt = qcur[qq];
    if (cnt > CAPQ) cnt = CAPQ;
    int k = t;
    for (; k + 768 < cnt; k += 1024) {
      unsigned int w0 = Q[qq][k], w1 = Q[qq][k + 256];
      unsigned int w2 = Q[qq][k + 512], w3 = Q[qq][k + 768];
      uint4 g0 = h1p8[w0 & 0x7FFFFu], g1 = h1p8[w1 & 0x7FFFFu];
      uint4 g2 = h1p8[w2 & 0x7FFFFu], g3 = h1p8[w3 & 0x7FFFFu];
      scat(w0, g0); scat(w1, g1); scat(w2, g2); scat(w3, g3);
    }
    for (; k < cnt; k += 256) {
      unsigned int w = Q[qq][k];
      scat(w, h1p8[w & 0x7FFFFu]);
    }
    __syncthreads();
  }

  int i = b * 256 + t;
  if (i >= N_NODES) return;
  float dinv = 1.0f / fmaxf((float)deg[t], 1.0f);
  v4u q0 = __builtin_nontemporal_load(&s2[(size_t)i * 2]);
  v4u q1 = __builtin_nontemporal_load(&s2[(size_t)i * 2 + 1]);
  float2 s0 = up2(q0.x), s1 = up2(q0.y), s2v = up2(q0.z), s3 = up2(q0.w);
  float2 s4 = up2(q1.x), s5 = up2(q1.y), s6 = up2(q1.z), s7 = up2(q1.w);
  float sv[16] = {s0.x, s0.y, s1.x, s1.y, s2v.x, s2v.y, s3.x, s3.y,
                  s4.x, s4.y, s5.x, s5.y, s6.x, s6.y, s7.x, s7.y};
  float o = sbo;
#pragma unroll
  for (int c = 0; c < 16; c++) {
    float h2 = fmaxf(acc[c][t] * dinv + sv[c] + sb2[c], 0.0f);
    o = fmaf(h2, sWo[c], o);
  }
  out[i] = 1.0f / (1.0f + expf(-o));
}

extern "C" void kernel_launch(void* const* d_in, const int* in_sizes, int n_in,
                              void* d_out, int out_size, void* d_ws, size_t ws_size,
                              hipStream_t stream) {
  const float* x    = (const float*)d_in[0];
  const int*   ei   = (const int*)d_in[1];
  const float* W1l  = (const float*)d_in[2];
  const float* W1r  = (const float*)d_in[3];
  const float* b1   = (const float*)d_in[4];
  const float* W2l  = (const float*)d_in[5];
  const float* W2r  = (const float*)d_in[6];
  const float* b2   = (const float*)d_in[7];
  const float* Wout = (const float*)d_in[8];
  const float* bout = (const float*)d_in[9];
  float* out = (float*)d_out;

  char* ws = (char*)d_ws;
  int* tot     = (int*)(ws + OFF_TOT);
  int* base    = (int*)(ws + OFF_BASE);
  int* fineCur = (int*)(ws + OFF_FCUR);
  int* sbCur   = (int*)(ws + OFF_SBCUR);
  int* auxBase = (int*)(ws + OFF_AUXB);
  uint2* xh8   = (uint2*)(ws + OFF_XH8);
  unsigned int* pairs = (unsigned int*)(ws + OFF_PAIRS);
  unsigned int* aux   = (unsigned int*)(ws + OFF_AUX);
  v4u* h1p8    = (v4u*)(ws + OFF_H1P8);
  v4u* s2      = (v4u*)(ws + OFF_S2);

  (void)hipMemsetAsync(tot, 0, NBUCKET * sizeof(int), stream);

  k_xcast<<<NB_USED, 256, 0, stream>>>(x, xh8);
  k_hist<<<NCH_H, 256, 0, stream>>>(ei, tot);
  k_scan<<<1, 256, 0, stream>>>(tot, base, fineCur, sbCur, auxBase);
  // half 0: super-buckets 0..31 (dst < 262144)
  k_passA<<<NCH_A, 256, 0, stream>>>(ei, sbCur, aux, 0);
  k_passB<<<32 * NSLICE, 256, 0, stream>>>(aux, base, auxBase, fineCur, pairs, 0);
  // half 1: super-buckets 32..63
  k_passA<<<NCH_A, 256, 0, stream>>>(ei, sbCur, aux, 1);
  k_passB<<<32 * NSLICE, 256, 0, stream>>>(aux, base, auxBase, fineCur, pairs, 1);
  // no k_sort: l1/l2 consume unsorted bucket streams via LDS accumulators
  k_l1<<<NB_USED, 256, 0, stream>>>(pairs, base, xh8, x, W1l, W1r, b1,
                                    W2l, W2r, h1p8, s2);
  k_l2<<<NB_USED, 256, 0, stream>>>(pairs, base, (const uint4*)h1p8, s2,
                                    b2, Wout, bout, out);
}

// Round 8
// 2175.879 us; speedup vs baseline: 1.1748x; 1.1748x over previous
//
#include <hip/hip_runtime.h>
#include <hip/hip_fp16.h>
#include <math.h>

#define N_NODES 500000
#define N_EDGES 16000000

#define NBUCKET 2048           // fine bucket = dst >> 8 (256 nodes)
#define NSB 64                 // super bucket = dst >> 13 (8192 nodes)
#define NSLICE 32              // slices per super bucket in pass B
#define NB_USED 1954           // ceil(500000/256)
#define BUCKET_CAP 9216        // mean 8192, sigma ~90 -> +11 sigma

#define NCH_H 500
#define CHUNK_H 32000          // 500*32000 = 16M ; /4 for uint4
#define NCH_A 1000
#define CHUNK_A 16000          // 1000*16000 = 16M ; /4 for uint4
#define T_A 4000               // multisplit tile (4 per chunk)
#define GPT 1000               // groups (of 4 edges) per tile
#define T_B 4000               // multisplit tile in pass B

// Workspace layout (bytes): (as round 4)
//   tot[0,8192) base[8192,16392) fineCur[16512,24704) sbCur[24704,24960)
//   auxBase[24960,25216) row[25600,2025600) xh8[4025600,8025600)
//   pairs[8025664,72025664) aux[72025664,105625664) overlaid:
//   h1p8[72025664,80025664) s2[80025664,96025664) degq[96025664,98025664)
#define OFF_TOT     0
#define OFF_BASE    8192
#define OFF_FCUR    16512
#define OFF_SBCUR   24704
#define OFF_AUXB    24960
#define OFF_ROW     25600
#define OFF_XH8     4025600
#define OFF_PAIRS   8025664
#define OFF_AUX     72025664
#define OFF_H1P8    72025664
#define OFF_S2      80025664
#define OFF_DEGQ    96025664

typedef float v2f __attribute__((ext_vector_type(2)));
typedef unsigned int v4u __attribute__((ext_vector_type(4)));

static __device__ inline float2 up2(unsigned int u) {
  __half2 h = *reinterpret_cast<__half2*>(&u);
  return __half22float2(h);
}
static __device__ inline unsigned int ph2(float a, float b) {
  __half2 h = __floats2half2_rn(a, b);
  return *reinterpret_cast<unsigned int*>(&h);
}
static __device__ inline unsigned int pk_fp8x4(float a, float b, float c, float d) {
  int u = __builtin_amdgcn_cvt_pk_fp8_f32(a, b, 0, false);
  u = __builtin_amdgcn_cvt_pk_fp8_f32(c, d, u, true);
  return (unsigned int)u;
}
static __device__ inline void acc8(float* a, uint2 g) {
  v2f f01 = __builtin_amdgcn_cvt_pk_f32_fp8((int)g.x, false);
  v2f f23 = __builtin_amdgcn_cvt_pk_f32_fp8((int)g.x, true);
  v2f f45 = __builtin_amdgcn_cvt_pk_f32_fp8((int)g.y, false);
  v2f f67 = __builtin_amdgcn_cvt_pk_f32_fp8((int)g.y, true);
  a[0] += f01.x; a[1] += f01.y; a[2] += f23.x; a[3] += f23.y;
  a[4] += f45.x; a[5] += f45.y; a[6] += f67.x; a[7] += f67.y;
}
static __device__ inline void acc16(float* a, uint4 g) {
  v2f f0 = __builtin_amdgcn_cvt_pk_f32_fp8((int)g.x, false);
  v2f f1 = __builtin_amdgcn_cvt_pk_f32_fp8((int)g.x, true);
  v2f f2 = __builtin_amdgcn_cvt_pk_f32_fp8((int)g.y, false);
  v2f f3 = __builtin_amdgcn_cvt_pk_f32_fp8((int)g.y, true);
  v2f f4 = __builtin_amdgcn_cvt_pk_f32_fp8((int)g.z, false);
  v2f f5 = __builtin_amdgcn_cvt_pk_f32_fp8((int)g.z, true);
  v2f f6 = __builtin_amdgcn_cvt_pk_f32_fp8((int)g.w, false);
  v2f f7 = __builtin_amdgcn_cvt_pk_f32_fp8((int)g.w, true);
  a[0] += f0.x;  a[1] += f0.y;  a[2] += f1.x;  a[3] += f1.y;
  a[4] += f2.x;  a[5] += f2.y;  a[6] += f3.x;  a[7] += f3.y;
  a[8] += f4.x;  a[9] += f4.y;  a[10] += f5.x; a[11] += f5.y;
  a[12] += f6.x; a[13] += f6.y; a[14] += f7.x; a[15] += f7.y;
}

// ---- 0: cast x to packed fp8 ---------------------------------------------
__global__ __launch_bounds__(256) void k_xcast(const float* __restrict__ x,
                                               uint2* __restrict__ xh8) {
  int i = blockIdx.x * 256 + threadIdx.x;
  if (i >= N_NODES) return;
  const float4* xp = (const float4*)(x + (size_t)i * 8);
  float4 a = xp[0], b = xp[1];
  uint2 v;
  v.x = pk_fp8x4(a.x, a.y, a.z, a.w);
  v.y = pk_fp8x4(b.x, b.y, b.z, b.w);
  xh8[i] = v;
}

// ---- 1: fine-bucket histogram -> tot (global atomics, 2048/block) --------
__global__ __launch_bounds__(256) void k_hist(const int* __restrict__ ei,
                                              int* __restrict__ tot) {
  __shared__ int hist[NBUCKET];
  int t = threadIdx.x;
  int c = blockIdx.x;
#pragma unroll
  for (int j = 0; j < NBUCKET / 256; j++) hist[t + j * 256] = 0;
  __syncthreads();
  int e0 = c * CHUNK_H;
  const int ng = CHUNK_H / 4;
  for (int g = t; g < ng; g += 256) {
    uint4 d4 = *(const uint4*)(ei + N_EDGES + e0 + g * 4);
    atomicAdd(&hist[d4.x >> 8], 1);
    atomicAdd(&hist[d4.y >> 8], 1);
    atomicAdd(&hist[d4.z >> 8], 1);
    atomicAdd(&hist[d4.w >> 8], 1);
  }
  __syncthreads();
#pragma unroll
  for (int j = 0; j < NBUCKET / 256; j++) {
    int b = t + j * 256;
    if (hist[b]) atomicAdd(&tot[b], hist[b]);
  }
}

// ---- 2: scan tot -> base; init fineCur, sbCur, auxBase -------------------
__global__ __launch_bounds__(256) void k_scan(const int* __restrict__ tot,
                                              int* __restrict__ base,
                                              int* __restrict__ fineCur,
                                              int* __restrict__ sbCur,
                                              int* __restrict__ auxBase) {
  __shared__ int lds[256];
  int t = threadIdx.x;
  int loc[8];
  int s = 0;
#pragma unroll
  for (int j = 0; j < 8; j++) {
    loc[j] = s;
    s += tot[t * 8 + j];
  }
  lds[t] = s;
  __syncthreads();
  for (int off = 1; off < 256; off <<= 1) {
    int v = (t >= off) ? lds[t - off] : 0;
    __syncthreads();
    lds[t] += v;
    __syncthreads();
  }
  int eb = (t > 0) ? lds[t - 1] : 0;
#pragma unroll
  for (int j = 0; j < 8; j++) {
    int idx = t * 8 + j;
    int v = eb + loc[j];
    base[idx] = v;
    fineCur[idx] = v;
  }
  if (t == 255) base[NBUCKET] = lds[255];
  if (t < NSB) {
    int v = (t > 0) ? lds[t * 4 - 1] : 0;  // base[t<<5]
    if (t >= 32) v -= lds[127];            // rebase half1 to aux offset 0
    sbCur[t] = v;
    auxBase[t] = v;
  }
}

// ---- 3: pass A — multisplit scatter, wave-aggregated (no per-edge LDS
// atomics: 32 ballots per 64 edges + one leader atomic per wave/stream).
// Tile loops are explicit so `ti` is wave-uniform.
__global__ __launch_bounds__(256) void k_passA(const int* __restrict__ ei,
                                               int* __restrict__ sbCur,
                                               unsigned int* __restrict__ aux,
                                               int half) {
  __shared__ unsigned int ldsW[T_A];
  __shared__ unsigned char sid[T_A];
  __shared__ int hist[4 * 32];
  __shared__ int gbase[4 * 32];
  __shared__ int loff[32];
  __shared__ int lcur[32];
  __shared__ int tot_s;
  int t = threadIdx.x;
  int lane = t & 63;
  unsigned long long ltm = (1ull << lane) - 1ull;
  int c = blockIdx.x;
  int e0 = c * CHUNK_A;
  int sb0 = half * 32;
  if (t < 128) hist[t] = 0;
  __syncthreads();
  // phase 1: per-(tile,stream) counts via ballot aggregation
  for (int ti = 0; ti < 4; ti++) {
    for (int g = ti * GPT + t; g < (ti + 1) * GPT; g += 256) {
      uint4 d4 = *(const uint4*)(ei + N_EDGES + e0 + g * 4);
      unsigned int dd[4] = {d4.x, d4.y, d4.z, d4.w};
#pragma unroll
      for (int j = 0; j < 4; j++) {
        int sb = (int)(dd[j] >> 13);
        int sl = ((sb >> 5) == half) ? (sb & 31) : -1;
        for (int s = 0; s < 32; s++) {
          unsigned long long m = __ballot(sl == s);
          if (!m) continue;
          if (lane == __ffsll((unsigned long long)m) - 1)
            atomicAdd(&hist[ti * 32 + s], (int)__popcll(m));
        }
      }
    }
  }
  __syncthreads();
  // phase 2: one global reservation per stream; per-tile bases
  if (t < 32) {
    int h0 = hist[t], h1 = hist[32 + t], h2 = hist[64 + t], h3 = hist[96 + t];
    int g = atomicAdd(&sbCur[sb0 + t], h0 + h1 + h2 + h3);
    gbase[t] = g;
    gbase[32 + t] = g + h0;
    gbase[64 + t] = g + h0 + h1;
    gbase[96 + t] = g + h0 + h1 + h2;
  }
  __syncthreads();
  for (int ti = 0; ti < 4; ti++) {
    if (t == 0) {
      int r = 0;
      for (int s = 0; s < 32; s++) {
        loff[s] = r; lcur[s] = r; r += hist[ti * 32 + s];
      }
      tot_s = r;
    }
    __syncthreads();
    int tb = e0 + ti * T_A;
    // phase 3: permute tile into LDS by stream, ballot-allocated positions
    for (int g = t; g < GPT; g += 256) {
      uint4 s4 = *(const uint4*)(ei + tb + g * 4);
      uint4 d4 = *(const uint4*)(ei + N_EDGES + tb + g * 4);
      unsigned int ss[4] = {s4.x, s4.y, s4.z, s4.w};
      unsigned int dd[4] = {d4.x, d4.y, d4.z, d4.w};
#pragma unroll
      for (int j = 0; j < 4; j++) {
        int sb = (int)(dd[j] >> 13);
        int sl = ((sb >> 5) == half) ? (sb & 31) : -1;
        unsigned int w = ss[j] | ((dd[j] & 8191u) << 19);
        int pos = -1;
        for (int s = 0; s < 32; s++) {
          unsigned long long m = __ballot(sl == s);
          if (!m) continue;
          int leader = __ffsll((unsigned long long)m) - 1;
          int bs = 0;
          if (lane == leader) bs = atomicAdd(&lcur[s], (int)__popcll(m));
          bs = __shfl(bs, leader);
          if (sl == s) pos = bs + (int)__popcll(m & ltm);
        }
        if (pos >= 0) { ldsW[pos] = w; sid[pos] = (unsigned char)sl; }
      }
    }
    __syncthreads();
    // phase 4: coalesced copy-out per stream segment
    int tot2 = tot_s;
    for (int k = t; k < tot2; k += 256) {
      int s = sid[k];
      __builtin_nontemporal_store(ldsW[k], &aux[gbase[ti * 32 + s] + (k - loff[s])]);
    }
    __syncthreads();
  }
}

// ---- 4: pass B — re-scatter into fine buckets, same ballot aggregation ---
__global__ __launch_bounds__(256) void k_passB(const unsigned int* __restrict__ aux,
                                               const int* __restrict__ base,
                                               const int* __restrict__ auxBase,
                                               int* __restrict__ fineCur,
                                               unsigned int* __restrict__ pairs,
                                               int half) {
  __shared__ unsigned int ldsW[T_B];
  __shared__ unsigned char sid[T_B];
  __shared__ int hist[4 * 32];
  __shared__ int gbase[4 * 32];
  __shared__ int loff[32];
  __shared__ int lcur[32];
  __shared__ int tot_s;
  int t = threadIdx.x;
  int lane = t & 63;
  unsigned long long ltm = (1ull << lane) - 1ull;
  int sbl = blockIdx.x / NSLICE;
  int sl2 = blockIdx.x % NSLICE;
  int sb = half * 32 + sbl;
  int aStart = auxBase[sb];
  int len = base[(sb + 1) << 5] - base[sb << 5];
  int per = (len + NSLICE - 1) / NSLICE;
  int lo = sl2 * per;
  int hi = lo + per;
  if (hi > len) hi = len;
  if (lo >= hi) return;                  // uniform across block
  int nt = (hi - lo + T_B - 1) / T_B;    // <= 4 (slice ~8200 edges)
  if (t < 128) hist[t] = 0;
  __syncthreads();
  // phase 1: per-(tile,stream) counts via ballot aggregation
  for (int ti = 0; ti < nt; ti++) {
    int tl = lo + ti * T_B;
    int te = tl + T_B; if (te > hi) te = hi;
    for (int k = tl + t; k < te; k += 256) {
      unsigned int w = aux[aStart + k];
      int s0 = (int)(w >> 27);
      for (int s = 0; s < 32; s++) {
        unsigned long long m = __ballot(s0 == s);
        if (!m) continue;
        if (lane == __ffsll((unsigned long long)m) - 1)
          atomicAdd(&hist[ti * 32 + s], (int)__popcll(m));
      }
    }
  }
  __syncthreads();
  // phase 2: one global reservation per fine stream; per-tile bases
  if (t < 32) {
    int h0 = hist[t], h1 = hist[32 + t], h2 = hist[64 + t], h3 = hist[96 + t];
    int g = atomicAdd(&fineCur[(sb << 5) + t], h0 + h1 + h2 + h3);
    gbase[t] = g;
    gbase[32 + t] = g + h0;
    gbase[64 + t] = g + h0 + h1;
    gbase[96 + t] = g + h0 + h1 + h2;
  }
  __syncthreads();
  for (int ti = 0; ti < nt; ti++) {
    if (t == 0) {
      int r = 0;
      for (int s = 0; s < 32; s++) {
        loff[s] = r; lcur[s] = r; r += hist[ti * 32 + s];
      }
      tot_s = r;
    }
    __syncthreads();
    int tl = lo + ti * T_B;
    int te = tl + T_B; if (te > hi) te = hi;
    // phase 3: permute tile into LDS, ballot-allocated positions
    for (int k = tl + t; k < te; k += 256) {
      unsigned int w = aux[aStart + k];
      int s0 = (int)(w >> 27);
      int pos = -1;
      for (int s = 0; s < 32; s++) {
        unsigned long long m = __ballot(s0 == s);
        if (!m) continue;
        int leader = __ffsll((unsigned long long)m) - 1;
        int bs = 0;
        if (lane == leader) bs = atomicAdd(&lcur[s], (int)__popcll(m));
        bs = __shfl(bs, leader);
        if (s0 == s) pos = bs + (int)__popcll(m & ltm);
      }
      if (pos >= 0) { ldsW[pos] = w; sid[pos] = (unsigned char)s0; }
    }
    __syncthreads();
    // phase 4: coalesced copy-out per stream segment
    int tot2 = tot_s;
    for (int k = t; k < tot2; k += 256) {
      int s = sid[k];
      __builtin_nontemporal_store(ldsW[k], &pairs[gbase[ti * 32 + s] + (k - loff[s])]);
    }
    __syncthreads();
  }
}

// ---- 5: within-bucket counting sort by (local dst, src-quadrant) ---------
__global__ __launch_bounds__(256) void k_sort(unsigned int* __restrict__ pairs,
                                              const int* __restrict__ base,
                                              int* __restrict__ row,
                                              unsigned int* __restrict__ degq) {
  __shared__ unsigned int sp[BUCKET_CAP];
  __shared__ int hist[1024];
  __shared__ int cur[1024];
  __shared__ int lds[256];
  int t = threadIdx.x;
  int b = blockIdx.x;
  int e0 = base[b];
  int n = base[b + 1] - e0;
  if (n > BUCKET_CAP) n = BUCKET_CAP;
  for (int k = t; k < n; k += 256) sp[k] = pairs[e0 + k];
#pragma unroll
  for (int j = 0; j < 4; j++) hist[t + j * 256] = 0;
  __syncthreads();
  for (int k = t; k < n; k += 256) {
    unsigned int p = sp[k];
    int key = (int)(((p >> 19) & 255u) << 2) | (int)((p & 0x7FFFFu) >> 17);
    atomicAdd(&hist[key], 1);
  }
  __syncthreads();
  int h0 = hist[4 * t], h1 = hist[4 * t + 1], h2 = hist[4 * t + 2], h3 = hist[4 * t + 3];
  int s = h0 + h1 + h2 + h3;
  lds[t] = s;
  __syncthreads();
  for (int off = 1; off < 256; off <<= 1) {
    int v = (t >= off) ? lds[t - off] : 0;
    __syncthreads();
    lds[t] += v;
    __syncthreads();
  }
  int ebase = (t > 0) ? lds[t - 1] : 0;
  cur[4 * t] = e0 + ebase;
  cur[4 * t + 1] = e0 + ebase + h0;
  cur[4 * t + 2] = e0 + ebase + h0 + h1;
  cur[4 * t + 3] = e0 + ebase + h0 + h1 + h2;
  int i = (b << 8) + t;
  if (i < N_NODES) {
    row[i] = e0 + ebase;
    degq[i] = (unsigned)h0 | ((unsigned)h1 << 8) | ((unsigned)h2 << 16) |
              ((unsigned)h3 << 24);
  }
  __syncthreads();
  for (int k = t; k < n; k += 256) {
    unsigned int p = sp[k];
    int key = (int)(((p >> 19) & 255u) << 2) | (int)((p & 0x7FFFFu) >> 17);
    int pos = atomicAdd(&cur[key], 1);
    pairs[pos] = p & 0x7FFFFu;
  }
}

// ---- 6: layer-1 node-centric aggregation, FLAT loop (round-4 best) -------
__global__ __launch_bounds__(256) void k_l1(
    const unsigned int* __restrict__ adj, const int* __restrict__ row,
    const unsigned int* __restrict__ degq, const uint2* __restrict__ xh8,
    const float* __restrict__ x,
    const float* __restrict__ W1l, const float* __restrict__ W1r,
    const float* __restrict__ b1,
    const float* __restrict__ W2l, const float* __restrict__ W2r,
    v4u* __restrict__ h1p8, v4u* __restrict__ s2) {
  __shared__ float sW1l[256], sW1r[256], sb1[32], sW2l[512], sW2r[512];
  int t = threadIdx.x;
  sW1l[t] = W1l[t];
  sW1r[t] = W1r[t];
  sW2l[t] = W2l[t];  sW2l[t + 256] = W2l[t + 256];
  sW2r[t] = W2r[t];  sW2r[t + 256] = W2r[t + 256];
  if (t < 32) sb1[t] = b1[t];
  __syncthreads();

  int i = blockIdx.x * 256 + t;
  if (i >= N_NODES) return;
  int rs = row[i];
  unsigned dq = degq[i];
  int d = (int)((dq & 255u) + ((dq >> 8) & 255u) + ((dq >> 16) & 255u) + (dq >> 24));

  float acc[8] = {0, 0, 0, 0, 0, 0, 0, 0};
  int j = 0;
  for (; j + 4 <= d; j += 4) {
    int a0 = (int)__builtin_nontemporal_load(&adj[rs + j + 0]);
    int a1 = (int)__builtin_nontemporal_load(&adj[rs + j + 1]);
    int a2 = (int)__builtin_nontemporal_load(&adj[rs + j + 2]);
    int a3 = (int)__builtin_nontemporal_load(&adj[rs + j + 3]);
    uint2 g0 = xh8[a0], g1 = xh8[a1], g2 = xh8[a2], g3 = xh8[a3];
    acc8(acc, g0); acc8(acc, g1); acc8(acc, g2); acc8(acc, g3);
  }
  for (; j < d; j++) {
    uint2 g = xh8[(int)__builtin_nontemporal_load(&adj[rs + j])];
    acc8(acc, g);
  }

  float dinv = 1.0f / fmaxf((float)d, 1.0f);
  float m[8];
#pragma unroll
  for (int f = 0; f < 8; f++) m[f] = acc[f] * dinv;
  const float4* xp = (const float4*)(x + (size_t)i * 8);
  float4 x0 = xp[0], x1 = xp[1];
  float xv[8] = {x0.x, x0.y, x0.z, x0.w, x1.x, x1.y, x1.z, x1.w};

  float h[32];
#pragma unroll
  for (int jj = 0; jj < 32; jj++) h[jj] = sb1[jj];
#pragma unroll
  for (int k = 0; k < 8; k++) {
#pragma unroll
    for (int jj = 0; jj < 32; jj++) {
      h[jj] = fmaf(m[k], sW1l[k * 32 + jj], h[jj]);
      h[jj] = fmaf(xv[k], sW1r[k * 32 + jj], h[jj]);
    }
  }
#pragma unroll
  for (int jj = 0; jj < 32; jj++) h[jj] = fmaxf(h[jj], 0.0f);

  float p[16], s[16];
#pragma unroll
  for (int jj = 0; jj < 16; jj++) { p[jj] = 0.0f; s[jj] = 0.0f; }
#pragma unroll
  for (int k = 0; k < 32; k++) {
#pragma unroll
    for (int jj = 0; jj < 16; jj++) {
      p[jj] = fmaf(h[k], sW2l[k * 16 + jj], p[jj]);
      s[jj] = fmaf(h[k], sW2r[k * 16 + jj], s[jj]);
    }
  }
  v4u hv;
  hv.x = pk_fp8x4(p[0], p[1], p[2], p[3]);
  hv.y = pk_fp8x4(p[4], p[5], p[6], p[7]);
  hv.z = pk_fp8x4(p[8], p[9], p[10], p[11]);
  hv.w = pk_fp8x4(p[12], p[13], p[14], p[15]);
  __builtin_nontemporal_store(hv, &h1p8[i]);
  v4u slo, shi;
  slo.x = ph2(s[0], s[1]);   slo.y = ph2(s[2], s[3]);
  slo.z = ph2(s[4], s[5]);   slo.w = ph2(s[6], s[7]);
  shi.x = ph2(s[8], s[9]);   shi.y = ph2(s[10], s[11]);
  shi.z = ph2(s[12], s[13]); shi.w = ph2(s[14], s[15]);
  __builtin_nontemporal_store(slo, &s2[(size_t)i * 2]);
  __builtin_nontemporal_store(shi, &s2[(size_t)i * 2 + 1]);
}

// ---- 7: layer-2 aggregation, src-quadrant phased WITH block sync (r6) ----
__global__ __launch_bounds__(256) void k_l2(
    const unsigned int* __restrict__ adj, const int* __restrict__ row,
    const unsigned int* __restrict__ degq, const uint4* __restrict__ h1p8,
    const v4u* __restrict__ s2, const float* __restrict__ b2,
    const float* __restrict__ Wout, const float* __restrict__ bout,
    float* __restrict__ out) {
  __shared__ float sb2[16], sWo[16], sbo;
  int t = threadIdx.x;
  if (t < 16) { sb2[t] = b2[t]; sWo[t] = Wout[t]; }
  if (t == 0) sbo = bout[0];
  __syncthreads();

  int i = blockIdx.x * 256 + t;
  bool act = i < N_NODES;
  int rs = act ? row[i] : 0;
  unsigned dq = act ? degq[i] : 0;
  int d = (int)((dq & 255u) + ((dq >> 8) & 255u) + ((dq >> 16) & 255u) + (dq >> 24));

  float acc[16];
#pragma unroll
  for (int jj = 0; jj < 16; jj++) acc[jj] = 0.0f;
  int off = 0;
#pragma unroll
  for (int q = 0; q < 4; q++) {
    int len = (int)((dq >> (8 * q)) & 255u);
    int js = rs + off;
    int j = 0;
    for (; j + 4 <= len; j += 4) {
      int a0 = (int)__builtin_nontemporal_load(&adj[js + j + 0]);
      int a1 = (int)__builtin_nontemporal_load(&adj[js + j + 1]);
      int a2 = (int)__builtin_nontemporal_load(&adj[js + j + 2]);
      int a3 = (int)__builtin_nontemporal_load(&adj[js + j + 3]);
      uint4 g0 = h1p8[a0], g1 = h1p8[a1], g2 = h1p8[a2], g3 = h1p8[a3];
      acc16(acc, g0); acc16(acc, g1); acc16(acc, g2); acc16(acc, g3);
    }
    for (; j < len; j++) {
      uint4 g = h1p8[(int)__builtin_nontemporal_load(&adj[js + j])];
      acc16(acc, g);
    }
    off += len;
    if (q < 3) __syncthreads();
  }

  if (!act) return;
  float dinv = 1.0f / fmaxf((float)d, 1.0f);
  v4u q0 = __builtin_nontemporal_load(&s2[(size_t)i * 2]);
  v4u q1 = __builtin_nontemporal_load(&s2[(size_t)i * 2 + 1]);
  float2 s0 = up2(q0.x), s1 = up2(q0.y), s2v = up2(q0.z), s3 = up2(q0.w);
  float2 s4 = up2(q1.x), s5 = up2(q1.y), s6 = up2(q1.z), s7 = up2(q1.w);
  float sv[16] = {s0.x, s0.y, s1.x, s1.y, s2v.x, s2v.y, s3.x, s3.y,
                  s4.x, s4.y, s5.x, s5.y, s6.x, s6.y, s7.x, s7.y};
  float o = sbo;
#pragma unroll
  for (int c = 0; c < 16; c++) {
    float h2 = fmaxf(acc[c] * dinv + sv[c] + sb2[c], 0.0f);
    o = fmaf(h2, sWo[c], o);
  }
  out[i] = 1.0f / (1.0f + expf(-o));
}

extern "C" void kernel_launch(void* const* d_in, const int* in_sizes, int n_in,
                              void* d_out, int out_size, void* d_ws, size_t ws_size,
                              hipStream_t stream) {
  const float* x    = (const float*)d_in[0];
  const int*   ei   = (const int*)d_in[1];
  const float* W1l  = (const float*)d_in[2];
  const float* W1r  = (const float*)d_in[3];
  const float* b1   = (const float*)d_in[4];
  const float* W2l  = (const float*)d_in[5];
  const float* W2r  = (const float*)d_in[6];
  const float* b2   = (const float*)d_in[7];
  const float* Wout = (const float*)d_in[8];
  const float* bout = (const float*)d_in[9];
  float* out = (float*)d_out;

  char* ws = (char*)d_ws;
  int* tot     = (int*)(ws + OFF_TOT);
  int* base    = (int*)(ws + OFF_BASE);
  int* fineCur = (int*)(ws + OFF_FCUR);
  int* sbCur   = (int*)(ws + OFF_SBCUR);
  int* auxBase = (int*)(ws + OFF_AUXB);
  int* row     = (int*)(ws + OFF_ROW);
  uint2* xh8   = (uint2*)(ws + OFF_XH8);
  unsigned int* pairs = (unsigned int*)(ws + OFF_PAIRS);
  unsigned int* aux   = (unsigned int*)(ws + OFF_AUX);
  v4u* h1p8    = (v4u*)(ws + OFF_H1P8);
  v4u* s2      = (v4u*)(ws + OFF_S2);
  unsigned int* degq = (unsigned int*)(ws + OFF_DEGQ);

  (void)hipMemsetAsync(tot, 0, NBUCKET * sizeof(int), stream);

  k_xcast<<<NB_USED, 256, 0, stream>>>(x, xh8);
  k_hist<<<NCH_H, 256, 0, stream>>>(ei, tot);
  k_scan<<<1, 256, 0, stream>>>(tot, base, fineCur, sbCur, auxBase);
  // half 0: super-buckets 0..31 (dst < 262144)
  k_passA<<<NCH_A, 256, 0, stream>>>(ei, sbCur, aux, 0);
  k_passB<<<32 * NSLICE, 256, 0, stream>>>(aux, base, auxBase, fineCur, pairs, 0);
  // half 1: super-buckets 32..63
  k_passA<<<NCH_A, 256, 0, stream>>>(ei, sbCur, aux, 1);
  k_passB<<<32 * NSLICE, 256, 0, stream>>>(aux, base, auxBase, fineCur, pairs, 1);
  k_sort<<<NBUCKET, 256, 0, stream>>>(pairs, base, row, degq);
  k_l1<<<NB_USED, 256, 0, stream>>>(pairs, row, degq, xh8, x, W1l, W1r, b1,
                                    W2l, W2r, h1p8, s2);
  k_l2<<<NB_USED, 256, 0, stream>>>(pairs, row, degq, (const uint4*)h1p8, s2,
                                    b2, Wout, bout, out);
}

// Round 9
// 828.569 us; speedup vs baseline: 3.0851x; 2.6261x over previous
//
#include <hip/hip_runtime.h>
#include <hip/hip_fp16.h>
#include <math.h>

#define N_NODES 500000
#define N_EDGES 16000000

#define NBUCKET 2048           // fine bucket = dst >> 8 (256 nodes)
#define NSB 64                 // super bucket = dst >> 13 (8192 nodes)
#define NSLICE 32              // slices per super bucket in pass B
#define NB_USED 1954           // ceil(500000/256)
#define BUCKET_CAP 9216        // mean 8192, sigma ~90 -> +11 sigma

#define NCH_H 500
#define CHUNK_H 32000          // 500*32000 = 16M ; /4 for uint4
#define NCH_A 1000
#define CHUNK_A 16000          // 1000*16000 = 16M ; /4 for uint4
#define T_A 4000               // multisplit tile (4 per chunk)
#define T_B 4000               // multisplit tile in pass B

// Workspace layout (bytes):
//   tot[0,8192) base[8192,16392) fineCur[16512,24704) sbCur[24704,24960)
//   auxBase[24960,25216) row[25600,2025600)
//   histB  [2,025,600, 2,537,600)   1000 blocks x 128 int (passA half-1 hist)
//   xh8[4025600,8025600) pairs[8025664,72025664) aux[72025664,105625664)
//   overlaid after aux dead: h1p8[72025664,80025664) s2[80025664,96025664)
//   degq[96025664,98025664)
#define OFF_TOT     0
#define OFF_BASE    8192
#define OFF_FCUR    16512
#define OFF_SBCUR   24704
#define OFF_AUXB    24960
#define OFF_ROW     25600
#define OFF_HISTB   2025600
#define OFF_XH8     4025600
#define OFF_PAIRS   8025664
#define OFF_AUX     72025664
#define OFF_H1P8    72025664
#define OFF_S2      80025664
#define OFF_DEGQ    96025664

typedef float v2f __attribute__((ext_vector_type(2)));
typedef unsigned int v4u __attribute__((ext_vector_type(4)));

static __device__ inline float2 up2(unsigned int u) {
  __half2 h = *reinterpret_cast<__half2*>(&u);
  return __half22float2(h);
}
static __device__ inline unsigned int ph2(float a, float b) {
  __half2 h = __floats2half2_rn(a, b);
  return *reinterpret_cast<unsigned int*>(&h);
}
static __device__ inline unsigned int pk_fp8x4(float a, float b, float c, float d) {
  int u = __builtin_amdgcn_cvt_pk_fp8_f32(a, b, 0, false);
  u = __builtin_amdgcn_cvt_pk_fp8_f32(c, d, u, true);
  return (unsigned int)u;
}
static __device__ inline void acc8(float* a, uint2 g) {
  v2f f01 = __builtin_amdgcn_cvt_pk_f32_fp8((int)g.x, false);
  v2f f23 = __builtin_amdgcn_cvt_pk_f32_fp8((int)g.x, true);
  v2f f45 = __builtin_amdgcn_cvt_pk_f32_fp8((int)g.y, false);
  v2f f67 = __builtin_amdgcn_cvt_pk_f32_fp8((int)g.y, true);
  a[0] += f01.x; a[1] += f01.y; a[2] += f23.x; a[3] += f23.y;
  a[4] += f45.x; a[5] += f45.y; a[6] += f67.x; a[7] += f67.y;
}
static __device__ inline void acc16(float* a, uint4 g) {
  v2f f0 = __builtin_amdgcn_cvt_pk_f32_fp8((int)g.x, false);
  v2f f1 = __builtin_amdgcn_cvt_pk_f32_fp8((int)g.x, true);
  v2f f2 = __builtin_amdgcn_cvt_pk_f32_fp8((int)g.y, false);
  v2f f3 = __builtin_amdgcn_cvt_pk_f32_fp8((int)g.y, true);
  v2f f4 = __builtin_amdgcn_cvt_pk_f32_fp8((int)g.z, false);
  v2f f5 = __builtin_amdgcn_cvt_pk_f32_fp8((int)g.z, true);
  v2f f6 = __builtin_amdgcn_cvt_pk_f32_fp8((int)g.w, false);
  v2f f7 = __builtin_amdgcn_cvt_pk_f32_fp8((int)g.w, true);
  a[0] += f0.x;  a[1] += f0.y;  a[2] += f1.x;  a[3] += f1.y;
  a[4] += f2.x;  a[5] += f2.y;  a[6] += f3.x;  a[7] += f3.y;
  a[8] += f4.x;  a[9] += f4.y;  a[10] += f5.x; a[11] += f5.y;
  a[12] += f6.x; a[13] += f6.y; a[14] += f7.x; a[15] += f7.y;
}

// ---- 0: cast x to packed fp8 ---------------------------------------------
__global__ __launch_bounds__(256) void k_xcast(const float* __restrict__ x,
                                               uint2* __restrict__ xh8) {
  int i = blockIdx.x * 256 + threadIdx.x;
  if (i >= N_NODES) return;
  const float4* xp = (const float4*)(x + (size_t)i * 8);
  float4 a = xp[0], b = xp[1];
  uint2 v;
  v.x = pk_fp8x4(a.x, a.y, a.z, a.w);
  v.y = pk_fp8x4(b.x, b.y, b.z, b.w);
  xh8[i] = v;
}

// ---- 1: fine-bucket histogram -> tot (global atomics, 2048/block) --------
__global__ __launch_bounds__(256) void k_hist(const int* __restrict__ ei,
                                              int* __restrict__ tot) {
  __shared__ int hist[NBUCKET];
  int t = threadIdx.x;
  int c = blockIdx.x;
#pragma unroll
  for (int j = 0; j < NBUCKET / 256; j++) hist[t + j * 256] = 0;
  __syncthreads();
  int e0 = c * CHUNK_H;
  const int ng = CHUNK_H / 4;
  for (int g = t; g < ng; g += 256) {
    uint4 d4 = *(const uint4*)(ei + N_EDGES + e0 + g * 4);
    atomicAdd(&hist[d4.x >> 8], 1);
    atomicAdd(&hist[d4.y >> 8], 1);
    atomicAdd(&hist[d4.z >> 8], 1);
    atomicAdd(&hist[d4.w >> 8], 1);
  }
  __syncthreads();
#pragma unroll
  for (int j = 0; j < NBUCKET / 256; j++) {
    int b = t + j * 256;
    if (hist[b]) atomicAdd(&tot[b], hist[b]);
  }
}

// ---- 2: scan tot -> base; init fineCur, sbCur, auxBase -------------------
__global__ __launch_bounds__(256) void k_scan(const int* __restrict__ tot,
                                              int* __restrict__ base,
                                              int* __restrict__ fineCur,
                                              int* __restrict__ sbCur,
                                              int* __restrict__ auxBase) {
  __shared__ int lds[256];
  int t = threadIdx.x;
  int loc[8];
  int s = 0;
#pragma unroll
  for (int j = 0; j < 8; j++) {
    loc[j] = s;
    s += tot[t * 8 + j];
  }
  lds[t] = s;
  __syncthreads();
  for (int off = 1; off < 256; off <<= 1) {
    int v = (t >= off) ? lds[t - off] : 0;
    __syncthreads();
    lds[t] += v;
    __syncthreads();
  }
  int eb = (t > 0) ? lds[t - 1] : 0;
#pragma unroll
  for (int j = 0; j < 8; j++) {
    int idx = t * 8 + j;
    int v = eb + loc[j];
    base[idx] = v;
    fineCur[idx] = v;
  }
  if (t == 255) base[NBUCKET] = lds[255];
  if (t < NSB) {
    int v = (t > 0) ? lds[t * 4 - 1] : 0;  // base[t<<5]
    if (t >= 32) v -= lds[127];            // rebase half1 to aux offset 0
    sbCur[t] = v;
    auxBase[t] = v;
  }
}

// ---- 3: pass A — LDS multisplit scatter (round-4 per-edge atomics).
// half 0 counts BOTH halves in phase 1 (same dst read) and saves half-1's
// per-tile histograms to histB; half 1 skips phase 1 entirely.
__global__ __launch_bounds__(256) void k_passA(const int* __restrict__ ei,
                                               int* __restrict__ sbCur,
                                               unsigned int* __restrict__ aux,
                                               int* __restrict__ histB,
                                               int half) {
  __shared__ unsigned int ldsW[T_A];
  __shared__ unsigned char sid[T_A];
  __shared__ int histA[4 * 64];   // both halves (phase 1 of half 0)
  __shared__ int hist[4 * 32];    // this half's counts
  __shared__ int gbase[4 * 32];
  __shared__ int loff[32];
  __shared__ int lcur[32];
  __shared__ int tot_s;
  int t = threadIdx.x;
  int c = blockIdx.x;
  int e0 = c * CHUNK_A;
  int sb0 = half * 32;
  if (half == 0) {
    histA[t] = 0;                 // 256 ints == blockDim
    __syncthreads();
    // phase 1: per-(tile,superbucket) counts for BOTH halves
    const int ng = CHUNK_A / 4;
    for (int g = t; g < ng; g += 256) {
      uint4 d4 = *(const uint4*)(ei + N_EDGES + e0 + g * 4);
      int tile = g / (T_A / 4);   // 4-edge group fully inside one tile
      unsigned int dd[4] = {d4.x, d4.y, d4.z, d4.w};
#pragma unroll
      for (int j = 0; j < 4; j++)
        atomicAdd(&histA[tile * 64 + (int)(dd[j] >> 13)], 1);
    }
    __syncthreads();
    if (t < 128) {
      int ti = t >> 5, s = t & 31;
      hist[t] = histA[ti * 64 + s];
      histB[c * 128 + t] = histA[ti * 64 + 32 + s];
    }
    __syncthreads();
  } else {
    if (t < 128) hist[t] = histB[c * 128 + t];
    __syncthreads();
  }
  // phase 2: one global reservation per stream; per-tile bases
  if (t < 32) {
    int h0 = hist[t], h1 = hist[32 + t], h2 = hist[64 + t], h3 = hist[96 + t];
    int g = atomicAdd(&sbCur[sb0 + t], h0 + h1 + h2 + h3);
    gbase[t] = g;
    gbase[32 + t] = g + h0;
    gbase[64 + t] = g + h0 + h1;
    gbase[96 + t] = g + h0 + h1 + h2;
  }
  __syncthreads();
  for (int ti = 0; ti < 4; ti++) {
    if (t == 0) {
      int r = 0;
      for (int s = 0; s < 32; s++) {
        loff[s] = r; lcur[s] = r; r += hist[ti * 32 + s];
      }
      tot_s = r;
    }
    __syncthreads();
    int tb = e0 + ti * T_A;
    const int ng = T_A / 4;
    // phase 3: permute tile into LDS by stream (per-edge LDS atomic — cheap,
    // 32 spread counters; ballot aggregation here was 4.5x slower, r8)
    for (int g = t; g < ng; g += 256) {
      uint4 s4 = *(const uint4*)(ei + tb + g * 4);
      uint4 d4 = *(const uint4*)(ei + N_EDGES + tb + g * 4);
      unsigned int ss[4] = {s4.x, s4.y, s4.z, s4.w};
      unsigned int dd[4] = {d4.x, d4.y, d4.z, d4.w};
#pragma unroll
      for (int j = 0; j < 4; j++) {
        int sb = (int)(dd[j] >> 13);
        if ((sb >> 5) == half) {
          int sl = sb & 31;
          int pos = atomicAdd(&lcur[sl], 1);
          ldsW[pos] = ss[j] | ((dd[j] & 8191u) << 19);
          sid[pos] = (unsigned char)sl;
        }
      }
    }
    __syncthreads();
    // phase 4: coalesced copy-out per stream segment
    int tot2 = tot_s;
    for (int k = t; k < tot2; k += 256) {
      int s = sid[k];
      __builtin_nontemporal_store(ldsW[k], &aux[gbase[ti * 32 + s] + (k - loff[s])]);
    }
    __syncthreads();
  }
}

// ---- 4: pass B — LDS multisplit re-scatter into fine buckets (round 4) ---
__global__ __launch_bounds__(256) void k_passB(const unsigned int* __restrict__ aux,
                                               const int* __restrict__ base,
                                               const int* __restrict__ auxBase,
                                               int* __restrict__ fineCur,
                                               unsigned int* __restrict__ pairs,
                                               int half) {
  __shared__ unsigned int ldsW[T_B];
  __shared__ unsigned char sid[T_B];
  __shared__ int hist[4 * 32];
  __shared__ int gbase[4 * 32];
  __shared__ int loff[32];
  __shared__ int lcur[32];
  __shared__ int tot_s;
  int t = threadIdx.x;
  int sbl = blockIdx.x / NSLICE;
  int sl = blockIdx.x % NSLICE;
  int sb = half * 32 + sbl;
  int aStart = auxBase[sb];
  int len = base[(sb + 1) << 5] - base[sb << 5];
  int per = (len + NSLICE - 1) / NSLICE;
  int lo = sl * per;
  int hi = lo + per;
  if (hi > len) hi = len;
  if (lo >= hi) return;                  // uniform across block
  int nt = (hi - lo + T_B - 1) / T_B;    // <= 4 (slice ~8200 edges)
  if (t < 128) hist[t] = 0;
  __syncthreads();
  // phase 1: per-(tile,stream) counts
  for (int k = lo + t; k < hi; k += 256) {
    unsigned int w = aux[aStart + k];
    int tile = (k - lo) / T_B;
    atomicAdd(&hist[tile * 32 + (int)(w >> 27)], 1);
  }
  __syncthreads();
  // phase 2: one global reservation per fine stream; per-tile bases
  if (t < 32) {
    int h0 = hist[t], h1 = hist[32 + t], h2 = hist[64 + t], h3 = hist[96 + t];
    int g = atomicAdd(&fineCur[(sb << 5) + t], h0 + h1 + h2 + h3);
    gbase[t] = g;
    gbase[32 + t] = g + h0;
    gbase[64 + t] = g + h0 + h1;
    gbase[96 + t] = g + h0 + h1 + h2;
  }
  __syncthreads();
  for (int ti = 0; ti < nt; ti++) {
    if (t == 0) {
      int r = 0;
      for (int s = 0; s < 32; s++) {
        loff[s] = r; lcur[s] = r; r += hist[ti * 32 + s];
      }
      tot_s = r;
    }
    __syncthreads();
    int tl = lo + ti * T_B;
    int te = tl + T_B;
    if (te > hi) te = hi;
    // phase 3: permute tile into LDS by fine stream (tile re-read is L2-hot)
    for (int k = tl + t; k < te; k += 256) {
      unsigned int w = aux[aStart + k];
      int s = (int)(w >> 27);
      int pos = atomicAdd(&lcur[s], 1);
      ldsW[pos] = w;
      sid[pos] = (unsigned char)s;
    }
    __syncthreads();
    // phase 4: coalesced copy-out per stream segment
    int tot2 = tot_s;
    for (int k = t; k < tot2; k += 256) {
      int s = sid[k];
      __builtin_nontemporal_store(ldsW[k], &pairs[gbase[ti * 32 + s] + (k - loff[s])]);
    }
    __syncthreads();
  }
}

// ---- 5: within-bucket counting sort by (local dst, src-quadrant) ---------
__global__ __launch_bounds__(256) void k_sort(unsigned int* __restrict__ pairs,
                                              const int* __restrict__ base,
                                              int* __restrict__ row,
                                              unsigned int* __restrict__ degq) {
  __shared__ unsigned int sp[BUCKET_CAP];
  __shared__ int hist[1024];
  __shared__ int cur[1024];
  __shared__ int lds[256];
  int t = threadIdx.x;
  int b = blockIdx.x;
  int e0 = base[b];
  int n = base[b + 1] - e0;
  if (n > BUCKET_CAP) n = BUCKET_CAP;
  for (int k = t; k < n; k += 256) sp[k] = pairs[e0 + k];
#pragma unroll
  for (int j = 0; j < 4; j++) hist[t + j * 256] = 0;
  __syncthreads();
  for (int k = t; k < n; k += 256) {
    unsigned int p = sp[k];
    int key = (int)(((p >> 19) & 255u) << 2) | (int)((p & 0x7FFFFu) >> 17);
    atomicAdd(&hist[key], 1);
  }
  __syncthreads();
  int h0 = hist[4 * t], h1 = hist[4 * t + 1], h2 = hist[4 * t + 2], h3 = hist[4 * t + 3];
  int s = h0 + h1 + h2 + h3;
  lds[t] = s;
  __syncthreads();
  for (int off = 1; off < 256; off <<= 1) {
    int v = (t >= off) ? lds[t - off] : 0;
    __syncthreads();
    lds[t] += v;
    __syncthreads();
  }
  int ebase = (t > 0) ? lds[t - 1] : 0;
  cur[4 * t] = e0 + ebase;
  cur[4 * t + 1] = e0 + ebase + h0;
  cur[4 * t + 2] = e0 + ebase + h0 + h1;
  cur[4 * t + 3] = e0 + ebase + h0 + h1 + h2;
  int i = (b << 8) + t;
  if (i < N_NODES) {
    row[i] = e0 + ebase;
    degq[i] = (unsigned)h0 | ((unsigned)h1 << 8) | ((unsigned)h2 << 16) |
              ((unsigned)h3 << 24);
  }
  __syncthreads();
  for (int k = t; k < n; k += 256) {
    unsigned int p = sp[k];
    int key = (int)(((p >> 19) & 255u) << 2) | (int)((p & 0x7FFFFu) >> 17);
    int pos = atomicAdd(&cur[key], 1);
    pairs[pos] = p & 0x7FFFFu;
  }
}

// ---- 6: layer-1 node-centric aggregation, FLAT loop (round-4 best) -------
__global__ __launch_bounds__(256) void k_l1(
    const unsigned int* __restrict__ adj, const int* __restrict__ row,
    const unsigned int* __restrict__ degq, const uint2* __restrict__ xh8,
    const float* __restrict__ x,
    const float* __restrict__ W1l, const float* __restrict__ W1r,
    const float* __restrict__ b1,
    const float* __restrict__ W2l, const float* __restrict__ W2r,
    v4u* __restrict__ h1p8, v4u* __restrict__ s2) {
  __shared__ float sW1l[256], sW1r[256], sb1[32], sW2l[512], sW2r[512];
  int t = threadIdx.x;
  sW1l[t] = W1l[t];
  sW1r[t] = W1r[t];
  sW2l[t] = W2l[t];  sW2l[t + 256] = W2l[t + 256];
  sW2r[t] = W2r[t];  sW2r[t + 256] = W2r[t + 256];
  if (t < 32) sb1[t] = b1[t];
  __syncthreads();

  int i = blockIdx.x * 256 + t;
  if (i >= N_NODES) return;
  int rs = row[i];
  unsigned dq = degq[i];
  int d = (int)((dq & 255u) + ((dq >> 8) & 255u) + ((dq >> 16) & 255u) + (dq >> 24));

  float acc[8] = {0, 0, 0, 0, 0, 0, 0, 0};
  int j = 0;
  for (; j + 4 <= d; j += 4) {
    int a0 = (int)__builtin_nontemporal_load(&adj[rs + j + 0]);
    int a1 = (int)__builtin_nontemporal_load(&adj[rs + j + 1]);
    int a2 = (int)__builtin_nontemporal_load(&adj[rs + j + 2]);
    int a3 = (int)__builtin_nontemporal_load(&adj[rs + j + 3]);
    uint2 g0 = xh8[a0], g1 = xh8[a1], g2 = xh8[a2], g3 = xh8[a3];
    acc8(acc, g0); acc8(acc, g1); acc8(acc, g2); acc8(acc, g3);
  }
  for (; j < d; j++) {
    uint2 g = xh8[(int)__builtin_nontemporal_load(&adj[rs + j])];
    acc8(acc, g);
  }

  float dinv = 1.0f / fmaxf((float)d, 1.0f);
  float m[8];
#pragma unroll
  for (int f = 0; f < 8; f++) m[f] = acc[f] * dinv;
  const float4* xp = (const float4*)(x + (size_t)i * 8);
  float4 x0 = xp[0], x1 = xp[1];
  float xv[8] = {x0.x, x0.y, x0.z, x0.w, x1.x, x1.y, x1.z, x1.w};

  float h[32];
#pragma unroll
  for (int jj = 0; jj < 32; jj++) h[jj] = sb1[jj];
#pragma unroll
  for (int k = 0; k < 8; k++) {
#pragma unroll
    for (int jj = 0; jj < 32; jj++) {
      h[jj] = fmaf(m[k], sW1l[k * 32 + jj], h[jj]);
      h[jj] = fmaf(xv[k], sW1r[k * 32 + jj], h[jj]);
    }
  }
#pragma unroll
  for (int jj = 0; jj < 32; jj++) h[jj] = fmaxf(h[jj], 0.0f);

  float p[16], s[16];
#pragma unroll
  for (int jj = 0; jj < 16; jj++) { p[jj] = 0.0f; s[jj] = 0.0f; }
#pragma unroll
  for (int k = 0; k < 32; k++) {
#pragma unroll
    for (int jj = 0; jj < 16; jj++) {
      p[jj] = fmaf(h[k], sW2l[k * 16 + jj], p[jj]);
      s[jj] = fmaf(h[k], sW2r[k * 16 + jj], s[jj]);
    }
  }
  v4u hv;
  hv.x = pk_fp8x4(p[0], p[1], p[2], p[3]);
  hv.y = pk_fp8x4(p[4], p[5], p[6], p[7]);
  hv.z = pk_fp8x4(p[8], p[9], p[10], p[11]);
  hv.w = pk_fp8x4(p[12], p[13], p[14], p[15]);
  __builtin_nontemporal_store(hv, &h1p8[i]);
  v4u slo, shi;
  slo.x = ph2(s[0], s[1]);   slo.y = ph2(s[2], s[3]);
  slo.z = ph2(s[4], s[5]);   slo.w = ph2(s[6], s[7]);
  shi.x = ph2(s[8], s[9]);   shi.y = ph2(s[10], s[11]);
  shi.z = ph2(s[12], s[13]); shi.w = ph2(s[14], s[15]);
  __builtin_nontemporal_store(slo, &s2[(size_t)i * 2]);
  __builtin_nontemporal_store(shi, &s2[(size_t)i * 2 + 1]);
}

// ---- 7: layer-2 aggregation, src-quadrant phased WITH block sync (r6) ----
__global__ __launch_bounds__(256) void k_l2(
    const unsigned int* __restrict__ adj, const int* __restrict__ row,
    const unsigned int* __restrict__ degq, const uint4* __restrict__ h1p8,
    const v4u* __restrict__ s2, const float* __restrict__ b2,
    const float* __restrict__ Wout, const float* __restrict__ bout,
    float* __restrict__ out) {
  __shared__ float sb2[16], sWo[16], sbo;
  int t = threadIdx.x;
  if (t < 16) { sb2[t] = b2[t]; sWo[t] = Wout[t]; }
  if (t == 0) sbo = bout[0];
  __syncthreads();

  int i = blockIdx.x * 256 + t;
  bool act = i < N_NODES;
  int rs = act ? row[i] : 0;
  unsigned dq = act ? degq[i] : 0;
  int d = (int)((dq & 255u) + ((dq >> 8) & 255u) + ((dq >> 16) & 255u) + (dq >> 24));

  float acc[16];
#pragma unroll
  for (int jj = 0; jj < 16; jj++) acc[jj] = 0.0f;
  int off = 0;
#pragma unroll
  for (int q = 0; q < 4; q++) {
    int len = (int)((dq >> (8 * q)) & 255u);
    int js = rs + off;
    int j = 0;
    for (; j + 4 <= len; j += 4) {
      int a0 = (int)__builtin_nontemporal_load(&adj[js + j + 0]);
      int a1 = (int)__builtin_nontemporal_load(&adj[js + j + 1]);
      int a2 = (int)__builtin_nontemporal_load(&adj[js + j + 2]);
      int a3 = (int)__builtin_nontemporal_load(&adj[js + j + 3]);
      uint4 g0 = h1p8[a0], g1 = h1p8[a1], g2 = h1p8[a2], g3 = h1p8[a3];
      acc16(acc, g0); acc16(acc, g1); acc16(acc, g2); acc16(acc, g3);
    }
    for (; j < len; j++) {
      uint4 g = h1p8[(int)__builtin_nontemporal_load(&adj[js + j])];
      acc16(acc, g);
    }
    off += len;
    if (q < 3) __syncthreads();
  }

  if (!act) return;
  float dinv = 1.0f / fmaxf((float)d, 1.0f);
  v4u q0 = __builtin_nontemporal_load(&s2[(size_t)i * 2]);
  v4u q1 = __builtin_nontemporal_load(&s2[(size_t)i * 2 + 1]);
  float2 s0 = up2(q0.x), s1 = up2(q0.y), s2v = up2(q0.z), s3 = up2(q0.w);
  float2 s4 = up2(q1.x), s5 = up2(q1.y), s6 = up2(q1.z), s7 = up2(q1.w);
  float sv[16] = {s0.x, s0.y, s1.x, s1.y, s2v.x, s2v.y, s3.x, s3.y,
                  s4.x, s4.y, s5.x, s5.y, s6.x, s6.y, s7.x, s7.y};
  float o = sbo;
#pragma unroll
  for (int c = 0; c < 16; c++) {
    float h2 = fmaxf(acc[c] * dinv + sv[c] + sb2[c], 0.0f);
    o = fmaf(h2, sWo[c], o);
  }
  out[i] = 1.0f / (1.0f + expf(-o));
}

extern "C" void kernel_launch(void* const* d_in, const int* in_sizes, int n_in,
                              void* d_out, int out_size, void* d_ws, size_t ws_size,
                              hipStream_t stream) {
  const float* x    = (const float*)d_in[0];
  const int*   ei   = (const int*)d_in[1];
  const float* W1l  = (const float*)d_in[2];
  const float* W1r  = (const float*)d_in[3];
  const float* b1   = (const float*)d_in[4];
  const float* W2l  = (const float*)d_in[5];
  const float* W2r  = (const float*)d_in[6];
  const float* b2   = (const float*)d_in[7];
  const float* Wout = (const float*)d_in[8];
  const float* bout = (const float*)d_in[9];
  float* out = (float*)d_out;

  char* ws = (char*)d_ws;
  int* tot     = (int*)(ws + OFF_TOT);
  int* base    = (int*)(ws + OFF_BASE);
  int* fineCur = (int*)(ws + OFF_FCUR);
  int* sbCur   = (int*)(ws + OFF_SBCUR);
  int* auxBase = (int*)(ws + OFF_AUXB);
  int* row     = (int*)(ws + OFF_ROW);
  int* histB   = (int*)(ws + OFF_HISTB);
  uint2* xh8   = (uint2*)(ws + OFF_XH8);
  unsigned int* pairs = (unsigned int*)(ws + OFF_PAIRS);
  unsigned int* aux   = (unsigned int*)(ws + OFF_AUX);
  v4u* h1p8    = (v4u*)(ws + OFF_H1P8);
  v4u* s2      = (v4u*)(ws + OFF_S2);
  unsigned int* degq = (unsigned int*)(ws + OFF_DEGQ);

  (void)hipMemsetAsync(tot, 0, NBUCKET * sizeof(int), stream);

  k_xcast<<<NB_USED, 256, 0, stream>>>(x, xh8);
  k_hist<<<NCH_H, 256, 0, stream>>>(ei, tot);
  k_scan<<<1, 256, 0, stream>>>(tot, base, fineCur, sbCur, auxBase);
  // half 0: super-buckets 0..31 (also records half-1 histograms in histB)
  k_passA<<<NCH_A, 256, 0, stream>>>(ei, sbCur, aux, histB, 0);
  k_passB<<<32 * NSLICE, 256, 0, stream>>>(aux, base, auxBase, fineCur, pairs, 0);
  // half 1: super-buckets 32..63 (phase 1 skipped via histB)
  k_passA<<<NCH_A, 256, 0, stream>>>(ei, sbCur, aux, histB, 1);
  k_passB<<<32 * NSLICE, 256, 0, stream>>>(aux, base, auxBase, fineCur, pairs, 1);
  k_sort<<<NBUCKET, 256, 0, stream>>>(pairs, base, row, degq);
  k_l1<<<NB_USED, 256, 0, stream>>>(pairs, row, degq, xh8, x, W1l, W1r, b1,
                                    W2l, W2r, h1p8, s2);
  k_l2<<<NB_USED, 256, 0, stream>>>(pairs, row, degq, (const uint4*)h1p8, s2,
                                    b2, Wout, bout, out);
}